// Round 9
// baseline (191.441 us; speedup 1.0000x reference)
//
#include <hip/hip_runtime.h>
#include <hip/hip_bf16.h>
#include <hip/hip_runtime_api.h>

#define BT 16
#define CCH 64
#define H 128
#define W 128
#define STR 8
#define NH 15
#define NW 15
#define L 225
#define HW (H * W)

// us LDS pitch (bf16 elems per c-row); 16B-multiple
#define UPITCH 264
// xal pitch (bf16 per pi-row); must be mult of 8 (16B rows)
#define XP 72
// conv LDS pitches
#define CP 72
#define MP 40

typedef __attribute__((ext_vector_type(8))) short short8;
typedef __attribute__((ext_vector_type(4))) float f32x4;
typedef __attribute__((ext_vector_type(4))) unsigned short ushort4_t;

__device__ __forceinline__ float lrelu(float v) { return v > 0.f ? v : 0.2f * v; }
__device__ __forceinline__ unsigned short f2bf(float v) {
  __hip_bfloat16 h = __float2bfloat16(v);
  unsigned short u;
  __builtin_memcpy(&u, &h, 2);
  return u;
}
__device__ __forceinline__ float bf2f(unsigned short u) {
  unsigned int x = ((unsigned int)u) << 16;
  float f;
  __builtin_memcpy(&f, &x, 4);
  return f;
}

// ---------------------------------------------------------------------------
// Prep: weights -> fragment order bf16 (W1r, W2r); spe/Wl -> bf16 row-major.
// ---------------------------------------------------------------------------
__global__ __launch_bounds__(256) void prep_w_k(
    const float* __restrict__ W1, const float* __restrict__ W2,
    const float* __restrict__ spe, const float* __restrict__ Wl,
    __hip_bfloat16* __restrict__ W1r, __hip_bfloat16* __restrict__ W2r,
    __hip_bfloat16* __restrict__ spe_r, __hip_bfloat16* __restrict__ wl_r) {
  const int idx = blockIdx.x * 256 + threadIdx.x;
  if (idx < 18432) {
    const int kk = idx >> 10, mc = (idx >> 5) & 31, ck = idx & 31;
    const int pos = kk >> 1, s = kk & 1;
    W1r[idx] = __float2bfloat16(W1[(mc * 64 + s * 32 + ck) * 9 + pos]);
    return;
  }
  int i = idx - 18432;
  if (i < 2048) { W2r[i] = __float2bfloat16(W2[i]); return; }
  i -= 2048;
  if (i < BT * CCH * CCH) { spe_r[i] = __float2bfloat16(spe[i]); return; }
  i -= BT * CCH * CCH;
  if (i < CCH * CCH) { wl_r[i] = __float2bfloat16(Wl[i]); return; }
}

// ---------------------------------------------------------------------------
// Prep: fea NCHW fp32 -> ft NHWC bf16.
// ---------------------------------------------------------------------------
__global__ __launch_bounds__(256) void fea_t_k(
    const float* __restrict__ fea, __hip_bfloat16* __restrict__ ft) {
  const int b = blockIdx.y;
  const int p0 = blockIdx.x * 256;
  const int tid = threadIdx.x;
#pragma unroll 1
  for (int it = 0; it < 8; ++it) {
    const int u = it * 256 + tid;
    const int px = u >> 3, g = u & 7;
    const int p = p0 + px;
    short8 v;
#pragma unroll
    for (int j = 0; j < 8; ++j)
      v[j] = (short)f2bf(fea[((size_t)b * CCH + g * 8 + j) * HW + p]);
    *(short8*)&ft[((size_t)b * HW + p) * CCH + g * 8] = v;
  }
}

// ---------------------------------------------------------------------------
// Prep: combined fold matrix T[b][pi][k] (bf16, dense 256x256).
// ---------------------------------------------------------------------------
__global__ __launch_bounds__(256) void spa_comb_k(
    const float* __restrict__ spa, __hip_bfloat16* __restrict__ T) {
  const int bp = blockIdx.x;  // b*256 + pi
  const int b = bp >> 8, pi = bp & 255;
  const int k = threadIdx.x;
  const int yi = pi >> 4, xi = pi & 15;
  const int ky = k >> 4, kx = k & 15;
  const float* sb = spa + (size_t)b * L * L;
  float acc = 0.f;
#pragma unroll
  for (int vy = 0; vy < 2; ++vy)
#pragma unroll
    for (int vx = 0; vx < 2; ++vx) {
      const int py = yi - vy, px = xi - vx;
      const int qy = ky - vy, qx = kx - vx;
      if (py >= 0 && py < NH && px >= 0 && px < NW && qy >= 0 && qy < NH &&
          qx >= 0 && qx < NW)
        acc += sb[(py * NW + px) * L + qy * NW + qx];
    }
  T[(size_t)bp * 256 + k] = __float2bfloat16(acc);
}

// ---------------------------------------------------------------------------
// Kernel A (MFMA): BasicBlock implicit GEMM -> fnh NHWC bf16 (unchanged).
// ---------------------------------------------------------------------------
__global__ __launch_bounds__(512) void bblock_mfma_k(
    const __hip_bfloat16* __restrict__ ft, const __hip_bfloat16* __restrict__ W1r,
    const __hip_bfloat16* __restrict__ W2r, __hip_bfloat16* __restrict__ fnh) {
  __shared__ __align__(16) short st[324 * CP];
  __shared__ __align__(16) short mids[256 * MP];
  const int b = blockIdx.z, ty0 = blockIdx.y * 16, tx0 = blockIdx.x * 16;
  const int tid = threadIdx.x;

  for (int i = tid; i < 2592; i += 512) {
    const int px = i >> 3, g = i & 7;
    const int iy = px / 18, ix = px - iy * 18;
    int gy = ty0 + iy - 1;
    gy = gy < 0 ? -gy : (gy > 127 ? 254 - gy : gy);
    int gx = tx0 + ix - 1;
    gx = gx < 0 ? -gx : (gx > 127 ? 254 - gx : gx);
    *(short8*)&st[px * CP + g * 8] =
        *(const short8*)&ft[((size_t)b * HW + gy * W + gx) * CCH + g * 8];
  }
  __syncthreads();

  const int w = tid >> 6, lane = tid & 63, lm = lane & 15, lk = lane >> 4;
  const short* w1 = (const short*)W1r;
  const short* w2 = (const short*)W2r;

  f32x4 acc[2][2];
#pragma unroll
  for (int mt = 0; mt < 2; ++mt)
#pragma unroll
    for (int t = 0; t < 2; ++t) acc[mt][t] = (f32x4){0.f, 0.f, 0.f, 0.f};

#pragma unroll
  for (int pos = 0; pos < 9; ++pos) {
    const int dy = pos / 3, dx = pos - dy * 3;
#pragma unroll
    for (int s = 0; s < 2; ++s) {
      short8 a0 = *(const short8*)&w1[((pos * 2 + s) * 32 + lm) * 32 + lk * 8];
      short8 a1 = *(const short8*)&w1[((pos * 2 + s) * 32 + 16 + lm) * 32 + lk * 8];
#pragma unroll
      for (int t = 0; t < 2; ++t) {
        const int p = (w * 2 + t + dy) * 18 + lm + dx;
        short8 bb = *(const short8*)&st[p * CP + s * 32 + lk * 8];
        acc[0][t] = __builtin_amdgcn_mfma_f32_16x16x32_bf16(a0, bb, acc[0][t], 0, 0, 0);
        acc[1][t] = __builtin_amdgcn_mfma_f32_16x16x32_bf16(a1, bb, acc[1][t], 0, 0, 0);
      }
    }
  }

#pragma unroll
  for (int t = 0; t < 2; ++t) {
    const int n = (w * 2 + t) * 16 + lm;
#pragma unroll
    for (int mt = 0; mt < 2; ++mt) {
      ushort4_t pk;
#pragma unroll
      for (int r = 0; r < 4; ++r) pk[r] = f2bf(lrelu(acc[mt][t][r]));
      *(ushort4_t*)&mids[n * MP + mt * 16 + lk * 4] = pk;
    }
  }
  __syncthreads();

  f32x4 acc2[4][2];
#pragma unroll
  for (int m2 = 0; m2 < 4; ++m2)
#pragma unroll
    for (int t = 0; t < 2; ++t) acc2[m2][t] = (f32x4){0.f, 0.f, 0.f, 0.f};

  short8 b2[2];
#pragma unroll
  for (int t = 0; t < 2; ++t)
    b2[t] = *(const short8*)&mids[((w * 2 + t) * 16 + lm) * MP + lk * 8];
#pragma unroll
  for (int m2 = 0; m2 < 4; ++m2) {
    short8 a2 = *(const short8*)&w2[(m2 * 16 + lm) * 32 + lk * 8];
#pragma unroll
    for (int t = 0; t < 2; ++t)
      acc2[m2][t] = __builtin_amdgcn_mfma_f32_16x16x32_bf16(a2, b2[t], acc2[m2][t], 0, 0, 0);
  }

  unsigned short* fo = (unsigned short*)fnh;
#pragma unroll
  for (int m2 = 0; m2 < 4; ++m2)
#pragma unroll
    for (int t = 0; t < 2; ++t) {
      const int y = ty0 + w * 2 + t, x = tx0 + lm;
      ushort4_t pk;
#pragma unroll
      for (int r = 0; r < 4; ++r) pk[r] = f2bf(lrelu(acc2[m2][t][r]));
      *(ushort4_t*)&fo[((size_t)b * HW + y * W + x) * CCH + m2 * 16 + lk * 4] = pk;
    }
}

// ---------------------------------------------------------------------------
// Kernel B (fused, MFMA): spatial GEMM + spectral residual + gated fusion.
// Block = (b,ky0,kx0); pixels (yi*8+ky0, xi*8+kx0), pi = yi*16+xi.
// GEMM1: xT[pi][c]  = T[pi][k]   @ us[c][k]^T      (M=256,N=64,K=256)
// GEMM2: resT[pi][c]= fnh[pi][d] @ spe_r[c][d]^T   (K=64; A gathered global)
// xa = 0.5(x+res) in regs -> bf16 repack xal[pi][c]
// GEMM3: xlT[pi][oc]= xal[pi][c] @ wl_r[oc][c]^T   (K=64)
// out = (2*xa)*wei + res*(1-2*wei) + f; single scattered NCHW store.
// All three D-tiles share lane layout: col=channel=lm, row=pi=lk*4+r.
// Waves: mtg=w>>1 -> mtiles {4mtg..4mtg+3}; wn=w&1 -> ctiles {2wn,2wn+1}.
// ---------------------------------------------------------------------------
__global__ __launch_bounds__(512) void spa_final_k(
    const __hip_bfloat16* __restrict__ fnh, const __hip_bfloat16* __restrict__ T,
    const __hip_bfloat16* __restrict__ spe_r, const __hip_bfloat16* __restrict__ wl_r,
    const float* __restrict__ bl, float* __restrict__ out) {
  __shared__ __align__(16) short us[CCH * UPITCH];  // 33.8 KB
  __shared__ __align__(16) short xal[256 * XP];     // 36.9 KB

  const int lb = ((int)blockIdx.x % 8) * 128 + (int)blockIdx.x / 8;
  const int b = lb >> 6, ky0 = (lb >> 3) & 7, kx0 = lb & 7;
  const int tid = threadIdx.x;

  const unsigned short* fb = (const unsigned short*)fnh + (size_t)b * HW * CCH;

  // stage us[c][k] (k = gy*16+gx grid pixel), swizzled 16B-block columns
  for (int i = tid; i < 2048; i += 512) {
    const int pos = i >> 3, g = i & 7;
    const int gy = pos >> 4, gx = pos & 15;
    const int blk = pos >> 3;
    short8 v = *(const short8*)&fb[((ky0 + 8 * gy) * W + kx0 + 8 * gx) * CCH + g * 8];
#pragma unroll
    for (int e = 0; e < 8; ++e) {
      const int c = g * 8 + e;
      const int sblk = (blk & ~7) | ((blk ^ (c >> 3)) & 7);
      us[c * UPITCH + sblk * 8 + (pos & 7)] = v[e];
    }
  }
  __syncthreads();

  const int w = tid >> 6, lane = tid & 63;
  const int lm = lane & 15, lk = lane >> 4;
  const int mtg = w >> 1, wn = w & 1;

  const short* tb = (const short*)T + (size_t)b * 256 * 256;
  const short* sp = (const short*)spe_r + (size_t)b * CCH * CCH;
  const short* wl = (const short*)wl_r;

  // GEMM1: xa[mi][ni] accumulates xT
  f32x4 xa[4][2], res[4][2];
#pragma unroll
  for (int mi = 0; mi < 4; ++mi)
#pragma unroll
    for (int ni = 0; ni < 2; ++ni) {
      xa[mi][ni] = (f32x4){0.f, 0.f, 0.f, 0.f};
      res[mi][ni] = (f32x4){0.f, 0.f, 0.f, 0.f};
    }

#pragma unroll
  for (int kk = 0; kk < 8; ++kk) {
    // B-frags from us (swizzled)
    short8 ub[2];
#pragma unroll
    for (int ni = 0; ni < 2; ++ni) {
      const int c = (wn * 2 + ni) * 16 + lm;
      const int kb = kk * 4 + lk;
      const int sblk = (kb & ~7) | ((kb ^ (c >> 3)) & 7);
      ub[ni] = *(const short8*)&us[c * UPITCH + sblk * 8];
    }
#pragma unroll
    for (int mi = 0; mi < 4; ++mi) {
      short8 ta = *(const short8*)&tb[((mtg * 4 + mi) * 16 + lm) * 256 + kk * 32 + lk * 8];
#pragma unroll
      for (int ni = 0; ni < 2; ++ni)
        xa[mi][ni] = __builtin_amdgcn_mfma_f32_16x16x32_bf16(ta, ub[ni], xa[mi][ni], 0, 0, 0);
    }
  }

  // GEMM2: resT from fnh gather (A) x spe rows (B), K=64
#pragma unroll
  for (int kk = 0; kk < 2; ++kk) {
    short8 sb[2];
#pragma unroll
    for (int ni = 0; ni < 2; ++ni) {
      const int c = (wn * 2 + ni) * 16 + lm;
      sb[ni] = *(const short8*)&sp[c * CCH + kk * 32 + lk * 8];
    }
#pragma unroll
    for (int mi = 0; mi < 4; ++mi) {
      const int yi = mtg * 4 + mi;  // pi row-tile = yi; lm = xi
      short8 fa = *(const short8*)&fb[((yi * 8 + ky0) * W + lm * 8 + kx0) * CCH + kk * 32 + lk * 8];
#pragma unroll
      for (int ni = 0; ni < 2; ++ni)
        res[mi][ni] = __builtin_amdgcn_mfma_f32_16x16x32_bf16(fa, sb[ni], res[mi][ni], 0, 0, 0);
    }
  }

  // xa = 0.5*(x + res); repack bf16 -> xal[pi][c]
#pragma unroll
  for (int mi = 0; mi < 4; ++mi)
#pragma unroll
    for (int ni = 0; ni < 2; ++ni) {
      const int c = (wn * 2 + ni) * 16 + lm;
#pragma unroll
      for (int r = 0; r < 4; ++r) {
        const float v = 0.5f * (xa[mi][ni][r] + res[mi][ni][r]);
        xa[mi][ni][r] = v;
        xal[((mtg * 4 + mi) * 16 + lk * 4 + r) * XP + c] = (short)f2bf(v);
      }
    }
  __syncthreads();

  // GEMM3 + gate + combine + store, per mtile (small live range)
  float blv[2];
#pragma unroll
  for (int ni = 0; ni < 2; ++ni) blv[ni] = bl[(wn * 2 + ni) * 16 + lm];

  float* ob = out + (size_t)b * CCH * HW;
#pragma unroll
  for (int mi = 0; mi < 4; ++mi) {
    const int mt = mtg * 4 + mi;
    f32x4 t3[2];
#pragma unroll
    for (int ni = 0; ni < 2; ++ni) t3[ni] = (f32x4){0.f, 0.f, 0.f, 0.f};
#pragma unroll
    for (int kk = 0; kk < 2; ++kk) {
      short8 xaf = *(const short8*)&xal[(mt * 16 + lm) * XP + kk * 32 + lk * 8];
#pragma unroll
      for (int ni = 0; ni < 2; ++ni) {
        const int oc = (wn * 2 + ni) * 16 + lm;
        short8 wb = *(const short8*)&wl[oc * CCH + kk * 32 + lk * 8];
        t3[ni] = __builtin_amdgcn_mfma_f32_16x16x32_bf16(xaf, wb, t3[ni], 0, 0, 0);
      }
    }
#pragma unroll
    for (int ni = 0; ni < 2; ++ni) {
      const int c = (wn * 2 + ni) * 16 + lm;
#pragma unroll
      for (int r = 0; r < 4; ++r) {
        const int pi = mt * 16 + lk * 4 + r;
        const float xl = lrelu(t3[ni][r] + blv[ni]);
        const float wei = 1.f / (1.f + __expf(-xl));
        // f from us (swizzled scalar read)
        const int blk = pi >> 3;
        const int sblk = (blk & ~7) | ((blk ^ (c >> 3)) & 7);
        const float fv = bf2f((unsigned short)us[c * UPITCH + sblk * 8 + (pi & 7)]);
        const float o = 2.f * xa[mi][ni][r] * wei + res[mi][ni][r] * (1.f - 2.f * wei) + fv;
        ob[c * HW + (mt * 8 + ky0) * W + (lk * 4 + r) * 8 + kx0] = o;
      }
    }
  }
}

// ---------------------------------------------------------------------------
extern "C" void kernel_launch(void* const* d_in, const int* in_sizes, int n_in,
                              void* d_out, int out_size, void* d_ws,
                              size_t ws_size, hipStream_t stream) {
  const float* fea = (const float*)d_in[0];
  const float* spa = (const float*)d_in[1];
  const float* spe = (const float*)d_in[2];
  const float* W1  = (const float*)d_in[3];
  const float* W2  = (const float*)d_in[4];
  const float* Wl  = (const float*)d_in[5];
  const float* bl  = (const float*)d_in[6];
  float* out = (float*)d_out;

  // ws layout (bytes)
  const size_t FT_BYTES  = (size_t)BT * HW * CCH * 2;   // 32 MB
  const size_t FNH_BYTES = (size_t)BT * HW * CCH * 2;   // 32 MB
  const size_t T_BYTES   = (size_t)BT * 256 * 256 * 2;  // 2 MB
  char* wsb = (char*)d_ws;
  __hip_bfloat16* ft  = (__hip_bfloat16*)wsb;
  __hip_bfloat16* fnh = (__hip_bfloat16*)(wsb + FT_BYTES);
  __hip_bfloat16* T   = (__hip_bfloat16*)(wsb + FT_BYTES + FNH_BYTES);
  char* wtb = wsb + FT_BYTES + FNH_BYTES + T_BYTES;
  __hip_bfloat16* W1r   = (__hip_bfloat16*)wtb;                   // 18432 el
  __hip_bfloat16* W2r   = (__hip_bfloat16*)(wtb + 36864);         // 2048 el
  __hip_bfloat16* spe_r = (__hip_bfloat16*)(wtb + 36864 + 4096);  // 65536 el
  __hip_bfloat16* wl_r  = (__hip_bfloat16*)(wtb + 36864 + 4096 + 131072);

  prep_w_k<<<dim3(352), 256, 0, stream>>>(W1, W2, spe, Wl, W1r, W2r, spe_r, wl_r);
  fea_t_k<<<dim3(HW / 256, BT), 256, 0, stream>>>(fea, ft);
  spa_comb_k<<<dim3(BT * 256), 256, 0, stream>>>(spa, T);
  bblock_mfma_k<<<dim3(8, 8, BT), 512, 0, stream>>>(ft, W1r, W2r, fnh);
  spa_final_k<<<dim3(BT * 64), 512, 0, stream>>>(fnh, T, spe_r, wl_r, bl, out);
}